// Round 9
// baseline (54.121 us; speedup 1.0000x reference)
//
#include <hip/hip_runtime.h>

// SegBrightnessLoss reduced to per-class {S_i, C_i} + global SS:
//   d2_i = S_i/N,  d3_i = (SS_i - 2 S_i^2/N + C_i S_i^2/N^2)/N,  sum_i SS_i = SS,
//   N = 4194304. One fused pass over x (50.3 MB fp32) + y (16.8 MB int32).
// R9: per-class accumulation moved from an 11-way cmp/cndmask/add VALU chain
// (~33 inst/pixel, ~9.9 us/CU -> co-critical with HBM) into per-lane-private
// LDS slots via ds_add_f32 (1 cndmask + 1 addr + 2 ds ops per pixel).
// Slot stride = 64 floats => bank = lane%32 (2-way, free). Counts <=16 -> f32 exact.

constexpr int kHW = 512 * 512;            // 262144
constexpr int kB = 16;
constexpr int kNPix = kB * kHW;           // 4194304 = N
constexpr int kNCls = 11;
constexpr int kNQ = 2 * kNCls + 1;        // 0..10 S_i, 11..21 C_i, 22 SS
constexpr int kBlocks = 1024;             // R7-best: 4 blocks/CU
constexpr int kThreads = 256;
// LDS rows per wave region: 0..10 S, 11 dead-S, 12..22 C, 23 dead-C, 24 ss
constexpr int kRows = 25;
constexpr int kRegion = kRows * 64;       // floats per wave region (1600)

__global__ __launch_bounds__(kThreads) void seg_main_kernel(
    const float* __restrict__ x, const int* __restrict__ y,
    double* __restrict__ pd) {
  const int tid = threadIdx.x, bid = blockIdx.x;
  const int lane = tid & 63, wave = tid >> 6;

  __shared__ float acc[4 * kRegion];      // 25600 B
  float* mybase = acc + wave * kRegion + lane;  // this lane's slot column
  // zero only the slots this lane will ever touch -> no barrier needed
#pragma unroll
  for (int q = 0; q < kRows; ++q) mybase[q * 64] = 0.f;

  float ss = 0.f;
  constexpr int kStride = kBlocks * kThreads;   // 262144 groups
  constexpr int kIters = (kNPix / 4) / kStride; // 4, exact
#pragma unroll
  for (int it = 0; it < kIters; ++it) {
    const int g = bid * kThreads + tid + it * kStride;
    const int p = g << 2;
    const int b = p >> 18;                // p / kHW  (kHW = 2^18)
    const int off = p & (kHW - 1);
    const float* xb = x + (size_t)b * 3 * kHW + off;
    const float4 x0 = *reinterpret_cast<const float4*>(xb);
    const float4 x1 = *reinterpret_cast<const float4*>(xb + kHW);
    const float4 x2 = *reinterpret_cast<const float4*>(xb + 2 * kHW);
    const int4 yv = *reinterpret_cast<const int4*>(y + p);

    const float xm[4] = {(x0.x + x1.x + x2.x) * (1.f / 3.f),
                         (x0.y + x1.y + x2.y) * (1.f / 3.f),
                         (x0.z + x1.z + x2.z) * (1.f / 3.f),
                         (x0.w + x1.w + x2.w) * (1.f / 3.f)};
    const int yy[4] = {yv.x, yv.y, yv.z, yv.w};
#pragma unroll
    for (int j = 0; j < 4; ++j) {
      const float m = xm[j];
      const bool nz = (m != 0.0f);        // exact a2==0 semantics of the ref
      ss = fmaf(nz ? m : 0.f, m, ss);     // m^2 iff nz
      const int cls = nz ? yy[j] : 11;    // row 11 (S) / 23 (C) are dead slots
      float* slot = mybase + cls * 64;
      atomicAdd(slot, m);                 // ds_add_f32, lane-private slot
      atomicAdd(slot + 12 * 64, 1.0f);    // count region at +12 rows
    }
  }
  mybase[24 * 64] = ss;                   // ss row, plain write
  __syncthreads();

  // ---- epilogue: 23 quantities x 8 lanes, each sums 4 regions x 8 floats ----
  if (tid < kNQ * 8) {
    const int q = tid >> 3, l = tid & 7;
    const int row = (q < 11) ? q : (q < 22 ? q + 1 : 24);
    const float* base = acc + row * 64 + l * 8;
    double dv = 0.0;
#pragma unroll
    for (int w = 0; w < 4; ++w) {
      const float4* p4 = reinterpret_cast<const float4*>(base + w * kRegion);
      const float4 a = p4[0], bq = p4[1];
      dv += (double)(((a.x + a.y) + (a.z + a.w)) +
                     ((bq.x + bq.y) + (bq.z + bq.w)));
    }
#pragma unroll
    for (int o = 4; o > 0; o >>= 1) dv += __shfl_down(dv, o, 8);
    if (l == 0) pd[(size_t)q * kBlocks + bid] = dv;  // quantity-major
  }
}

__global__ __launch_bounds__(1024) void seg_final_kernel(
    const double* __restrict__ pd, float* __restrict__ out) {
  __shared__ double tot[kNQ];
  const int q = threadIdx.x >> 5;         // 32 lanes per quantity
  const int lane = threadIdx.x & 31;
  if (q < kNQ) {
    double v = 0.0;
#pragma unroll
    for (int j = 0; j < kBlocks / 32; ++j)   // 32 unrolled independent loads
      v += pd[(size_t)q * kBlocks + lane + 32 * j];
#pragma unroll
    for (int o = 16; o > 0; o >>= 1) v += __shfl_down(v, o, 32);
    if (lane == 0) tot[q] = v;
  }
  __syncthreads();
  if (threadIdx.x == 0) {
    const double N = (double)kNPix;
    double acc2 = tot[2 * kNCls];         // SS_total
    for (int i = 0; i < kNCls; ++i) {
      const double S = tot[i];
      const double C = tot[kNCls + i];
      acc2 += S * S * (C / N - 2.0) / N;  // -2 S^2/N + C S^2/N^2
    }
    out[0] = (float)(acc2 / N);
  }
}

extern "C" void kernel_launch(void* const* d_in, const int* in_sizes, int n_in,
                              void* d_out, int out_size, void* d_ws, size_t ws_size,
                              hipStream_t stream) {
  const float* x = (const float*)d_in[0];
  const int* y = (const int*)d_in[1];
  float* out = (float*)d_out;
  double* pd = (double*)d_ws;             // 23 * 1024 * 8 = 188 KB

  seg_main_kernel<<<kBlocks, kThreads, 0, stream>>>(x, y, pd);
  seg_final_kernel<<<1, 1024, 0, stream>>>(pd, out);
}

// Round 10
// 22.134 us; speedup vs baseline: 2.4451x; 2.4451x over previous
//
#include <hip/hip_runtime.h>
#include <hip/hip_fp16.h>

// SegBrightnessLoss reduced to per-class {S_i, C_i} + global SS:
//   d2_i = S_i/N,  d3_i = (SS_i - 2 S_i^2/N + C_i S_i^2/N^2)/N,  sum_i SS_i = SS.
// R10: back to R7 skeleton (best, 21.6us; VALU-bound at ~9.9us by the
// 2cy/inst model confirmed by the R4->R7 delta). The 11-class f32 chain
// (33 inst/px) becomes a packed-f16 one-hot + 6x v_pk_fma_f16 (~20 inst/px).
// Channel-sum s=3m accumulated raw (S/3, SS/9 rescaled in the f64 finale;
// s==0 <=> m==0 exactly). Counts stay in the exact u64 5-bit pack.
// f16 worst-case bias on d ~ 8e-6 << 4.7e-3 threshold.

constexpr int kHW = 512 * 512;            // 262144
constexpr int kB = 16;
constexpr int kNPix = kB * kHW;           // 4194304 = N
constexpr int kNCls = 11;
constexpr int kNQ = 2 * kNCls + 1;        // 0..10 S'_i(=3S), 11..21 C_i, 22 SS'(=9SS)
constexpr int kBlocks = 1024;             // 4 blocks/CU (R7-best)
constexpr int kThreads = 256;

__global__ __launch_bounds__(kThreads) void seg_main_kernel(
    const float* __restrict__ x, const int* __restrict__ y,
    double* __restrict__ pd) {
  const int tid = threadIdx.x, bid = blockIdx.x;

  __half2 acc[6];                          // 12 f16 class-sums (11 dead)
#pragma unroll
  for (int r = 0; r < 6; ++r) acc[r] = __builtin_bit_cast(__half2, 0u);
  unsigned long long pack = 0ull;          // 11 counts in 5-bit fields
  float ss = 0.f;

  constexpr int kStride = kBlocks * kThreads;   // 262144
  constexpr int kIters = (kNPix / 4) / kStride; // 4, exact
#pragma unroll
  for (int it = 0; it < kIters; ++it) {
    const int g = bid * kThreads + tid + it * kStride;
    const int p = g << 2;
    const int b = p >> 18;                 // p / kHW  (kHW = 2^18)
    const int off = p & (kHW - 1);
    const float* xb = x + (size_t)b * 3 * kHW + off;
    const float4 x0 = *reinterpret_cast<const float4*>(xb);
    const float4 x1 = *reinterpret_cast<const float4*>(xb + kHW);
    const float4 x2 = *reinterpret_cast<const float4*>(xb + 2 * kHW);
    const int4 yv = *reinterpret_cast<const int4*>(y + p);

    const float sv4[4] = {x0.x + x1.x + x2.x, x0.y + x1.y + x2.y,
                          x0.z + x1.z + x2.z, x0.w + x1.w + x2.w};
    const int yy[4] = {yv.x, yv.y, yv.z, yv.w};
#pragma unroll
    for (int j = 0; j < 4; ++j) {
      const float sv = sv4[j];             // = 3*m; sv==0 <=> m==0 exactly
      ss = fmaf(sv, sv, ss);               // 0 contributes 0: no guard needed
      const int cls = (sv != 0.f) ? yy[j] : 11;   // class 11 = dead slot
      // one-hot f16 pair set: 0x3C00 at 16-bit slot (cls&3) of window cls>>2
      const unsigned long long oh = 0x3C00ull << ((cls & 3) << 4);
      const unsigned lo = (unsigned)oh, hi = (unsigned)(oh >> 32);
      const int w = cls >> 2;
      unsigned pr0 = (w == 0) ? lo : 0u, pr1 = (w == 0) ? hi : 0u;
      unsigned pr2 = (w == 1) ? lo : 0u, pr3 = (w == 1) ? hi : 0u;
      unsigned pr4 = (w == 2) ? lo : 0u, pr5 = (w == 2) ? hi : 0u;
      const __half2 m2 = __half2half2(__float2half(sv));
      acc[0] = __hfma2(__builtin_bit_cast(__half2, pr0), m2, acc[0]);
      acc[1] = __hfma2(__builtin_bit_cast(__half2, pr1), m2, acc[1]);
      acc[2] = __hfma2(__builtin_bit_cast(__half2, pr2), m2, acc[2]);
      acc[3] = __hfma2(__builtin_bit_cast(__half2, pr3), m2, acc[3]);
      acc[4] = __hfma2(__builtin_bit_cast(__half2, pr4), m2, acc[4]);
      acc[5] = __hfma2(__builtin_bit_cast(__half2, pr5), m2, acc[5]);
      pack += 1ull << (5 * cls);           // field 11 = bits 55..59 (dead)
    }
  }

  // ---- per-thread 23 quantities ----
  float qv[kNQ];
#pragma unroll
  for (int r = 0; r < 6; ++r) {
    const float2 f2 = __half22float2(acc[r]);   // accf[2r]=x(lo), accf[2r+1]=y
    if (2 * r < kNCls) qv[2 * r] = f2.x;
    if (2 * r + 1 < kNCls) qv[2 * r + 1] = f2.y;
  }
#pragma unroll
  for (int i = 0; i < kNCls; ++i)
    qv[kNCls + i] = (float)((unsigned)(pack >> (5 * i)) & 31u);
  qv[2 * kNCls] = ss;

  // ---- block epilogue: LDS transpose, 8 lanes per quantity (R7) ----
  __shared__ float arr[kNQ][kThreads];
#pragma unroll
  for (int q = 0; q < kNQ; ++q) arr[q][tid] = qv[q];
  __syncthreads();

  if (tid < kNQ * 8) {
    const int q = tid >> 3, l = tid & 7;
    const float4* row = reinterpret_cast<const float4*>(arr[q]);
    double dv = 0.0;
#pragma unroll
    for (int jj = 0; jj < kThreads / 32; ++jj) {
      const float4 v = row[l + 8 * jj];
      dv += (double)((v.x + v.y) + (v.z + v.w));
    }
#pragma unroll
    for (int o = 4; o > 0; o >>= 1) dv += __shfl_down(dv, o, 8);
    if (l == 0) pd[(size_t)q * kBlocks + bid] = dv;  // quantity-major
  }
}

__global__ __launch_bounds__(1024) void seg_final_kernel(
    const double* __restrict__ pd, float* __restrict__ out) {
  __shared__ double tot[kNQ];
  const int q = threadIdx.x >> 5;          // 32 lanes per quantity
  const int lane = threadIdx.x & 31;
  if (q < kNQ) {
    double v = 0.0;
#pragma unroll
    for (int j = 0; j < kBlocks / 32; ++j)  // 32 unrolled independent loads
      v += pd[(size_t)q * kBlocks + lane + 32 * j];
#pragma unroll
    for (int o = 16; o > 0; o >>= 1) v += __shfl_down(v, o, 32);
    if (lane == 0) tot[q] = v;
  }
  __syncthreads();
  if (threadIdx.x == 0) {
    const double N = (double)kNPix;
    double acc2 = tot[2 * kNCls] / 9.0;    // SS = ss'/9
    for (int i = 0; i < kNCls; ++i) {
      const double S = tot[i] / 3.0;       // S = S'/3
      const double C = tot[kNCls + i];
      acc2 += S * S * (C / N - 2.0) / N;   // -2 S^2/N + C S^2/N^2
    }
    out[0] = (float)(acc2 / N);
  }
}

extern "C" void kernel_launch(void* const* d_in, const int* in_sizes, int n_in,
                              void* d_out, int out_size, void* d_ws, size_t ws_size,
                              hipStream_t stream) {
  const float* x = (const float*)d_in[0];
  const int* y = (const int*)d_in[1];
  float* out = (float*)d_out;
  double* pd = (double*)d_ws;              // 23 * 1024 * 8 = 188 KB

  seg_main_kernel<<<kBlocks, kThreads, 0, stream>>>(x, y, pd);
  seg_final_kernel<<<1, 1024, 0, stream>>>(pd, out);
}

// Round 12
// 22.016 us; speedup vs baseline: 2.4583x; 1.0054x over previous
//
#include <hip/hip_runtime.h>

// SegBrightnessLoss reduced to per-class {S_i, C_i} + global SS:
//   d2_i = S_i/N,  d3_i = (SS_i - 2 S_i^2/N + C_i S_i^2/N^2)/N,  sum_i SS_i = SS,
//   N = 4194304. One fused pass over x (50.3 MB fp32) + y (16.8 MB int32).
// R12 (= R11 resubmitted after infra failure): break the load->drain->compute
// convoy. Plain __launch_bounds__(256) made the compiler target 8 waves/EU
// (64-VGPR cap, R9 showed VGPR=40), so the 16 loads could not be hoisted and
// every wave stalled on vmcnt each iteration (VALU+mem SERIAL fits R1/R4/R7/R8
// timings). Fix: LB(256,4) (128-VGPR cap = same 4 blocks/CU) + explicit
// depth-4 hoist: issue all 16 loads, then compute 4 iterations as they drain.

constexpr int kHW = 512 * 512;            // 262144
constexpr int kB = 16;
constexpr int kNPix = kB * kHW;           // 4194304 = N
constexpr int kNCls = 11;
constexpr int kNQ = 2 * kNCls + 1;        // 0..10 S_i, 11..21 C_i, 22 SS
constexpr int kBlocks = 1024;             // 4 blocks/CU
constexpr int kThreads = 256;
constexpr int kStride = kBlocks * kThreads;    // 262144
constexpr int kIters = (kNPix / 4) / kStride;  // 4, exact

__global__ __launch_bounds__(kThreads, 4) void seg_main_kernel(
    const float* __restrict__ x, const int* __restrict__ y,
    double* __restrict__ pd) {
  const int tid = threadIdx.x, bid = blockIdx.x;

  float s[kNCls];
#pragma unroll
  for (int i = 0; i < kNCls; ++i) s[i] = 0.f;
  float ss = 0.f;
  unsigned long long pack = 0ull;          // 11 counts in 5-bit fields

  // ---- phase 1: issue ALL 16 loads (depth-4 hoist) ----
  float4 vx0[kIters], vx1[kIters], vx2[kIters];
  int4 vy[kIters];
#pragma unroll
  for (int it = 0; it < kIters; ++it) {
    const int g = bid * kThreads + tid + it * kStride;
    const int p = g << 2;
    const int b = p >> 18;                 // p / kHW  (kHW = 2^18)
    const int off = p & (kHW - 1);
    const float* xb = x + (size_t)b * 3 * kHW + off;
    vx0[it] = *reinterpret_cast<const float4*>(xb);
    vx1[it] = *reinterpret_cast<const float4*>(xb + kHW);
    vx2[it] = *reinterpret_cast<const float4*>(xb + 2 * kHW);
    vy[it] = *reinterpret_cast<const int4*>(y + p);
  }

  // ---- phase 2: compute as the loads drain ----
#pragma unroll
  for (int it = 0; it < kIters; ++it) {
    const float4 x0 = vx0[it], x1 = vx1[it], x2 = vx2[it];
    const int4 yv = vy[it];
    const float xm[4] = {(x0.x + x1.x + x2.x) * (1.f / 3.f),
                         (x0.y + x1.y + x2.y) * (1.f / 3.f),
                         (x0.z + x1.z + x2.z) * (1.f / 3.f),
                         (x0.w + x1.w + x2.w) * (1.f / 3.f)};
    const int yy[4] = {yv.x, yv.y, yv.z, yv.w};
#pragma unroll
    for (int j = 0; j < 4; ++j) {
      const float m = xm[j];
      const bool nz = (m != 0.0f);         // exact a2==0 semantics of the ref
      const float mq = nz ? m : 0.f;
      ss = fmaf(mq, m, ss);                // m^2 iff nz
      const int cls = nz ? yy[j] : 12;     // fold nz into the class id once
      pack += 1ull << (5 * cls);           // all 11 counts in one add
#pragma unroll
      for (int i = 0; i < kNCls; ++i)
        s[i] += (cls == i) ? m : 0.f;      // cmp + cndmask + add
    }
  }

  // ---- per-thread 23 quantities ----
  float qv[kNQ];
#pragma unroll
  for (int i = 0; i < kNCls; ++i) qv[i] = s[i];
#pragma unroll
  for (int i = 0; i < kNCls; ++i)
    qv[kNCls + i] = (float)((unsigned)(pack >> (5 * i)) & 31u);
  qv[2 * kNCls] = ss;

  // ---- block epilogue: LDS transpose, 8 lanes per quantity ----
  __shared__ float arr[kNQ][kThreads];
#pragma unroll
  for (int q = 0; q < kNQ; ++q) arr[q][tid] = qv[q];
  __syncthreads();

  if (tid < kNQ * 8) {
    const int q = tid >> 3, l = tid & 7;
    const float4* row = reinterpret_cast<const float4*>(arr[q]);
    double dv = 0.0;
#pragma unroll
    for (int jj = 0; jj < kThreads / 32; ++jj) {
      const float4 v = row[l + 8 * jj];
      dv += (double)((v.x + v.y) + (v.z + v.w));
    }
#pragma unroll
    for (int o = 4; o > 0; o >>= 1) dv += __shfl_down(dv, o, 8);
    if (l == 0) pd[(size_t)q * kBlocks + bid] = dv;  // quantity-major
  }
}

__global__ __launch_bounds__(1024, 4) void seg_final_kernel(
    const double* __restrict__ pd, float* __restrict__ out) {
  __shared__ double tot[kNQ];
  const int q = threadIdx.x >> 5;          // 32 lanes per quantity
  const int lane = threadIdx.x & 31;
  if (q < kNQ) {
    double v = 0.0;
#pragma unroll
    for (int j = 0; j < kBlocks / 32; ++j)  // 32 unrolled independent loads
      v += pd[(size_t)q * kBlocks + lane + 32 * j];
#pragma unroll
    for (int o = 16; o > 0; o >>= 1) v += __shfl_down(v, o, 32);
    if (lane == 0) tot[q] = v;
  }
  __syncthreads();
  if (threadIdx.x == 0) {
    const double N = (double)kNPix;
    double acc2 = tot[2 * kNCls];          // SS_total
    for (int i = 0; i < kNCls; ++i) {
      const double S = tot[i];
      const double C = tot[kNCls + i];
      acc2 += S * S * (C / N - 2.0) / N;   // -2 S^2/N + C S^2/N^2
    }
    out[0] = (float)(acc2 / N);
  }
}

extern "C" void kernel_launch(void* const* d_in, const int* in_sizes, int n_in,
                              void* d_out, int out_size, void* d_ws, size_t ws_size,
                              hipStream_t stream) {
  const float* x = (const float*)d_in[0];
  const int* y = (const int*)d_in[1];
  float* out = (float*)d_out;
  double* pd = (double*)d_ws;              // 23 * 1024 * 8 = 188 KB

  seg_main_kernel<<<kBlocks, kThreads, 0, stream>>>(x, y, pd);
  seg_final_kernel<<<1, 1024, 0, stream>>>(pd, out);
}

// Round 13
// 19.305 us; speedup vs baseline: 2.8035x; 1.1404x over previous
//
#include <hip/hip_runtime.h>

// SegBrightnessLoss reduced to per-class {S_i, C_i} + global SS:
//   d2_i = S_i/N,  d3_i = (SS_i - 2 S_i^2/N + C_i S_i^2/N^2)/N,  sum_i SS_i = SS,
//   N = 4194304. One fused pass over x (50.3 MB fp32) + y (16.8 MB int32).
// R13: (1) fixed-point packed class-sums: q = round(768*m) accumulated into
// 6 u32 regs of two 16-bit fields (plain adds, no carry: q<=768*16=12288
// per field), 6 routing triples instead of 11; counts stay in the exact
// u64 5-bit pack. Block partials are INTEGER-exact in f32.
// (2) contiguous 4096-px slab per block (scalar bases + 13-bit imm offsets,
// 4x fewer pages touched per thread). (3) f32 partials, float4 finale.
// Quantization audit: worst-case systematic dS/S ~ 1.3e-3 -> delta-d ~1e-4
// << 4.7e-3 threshold; realistic (uniform data) ~1e-6.

constexpr int kHW = 512 * 512;            // 262144
constexpr int kB = 16;
constexpr int kNPix = kB * kHW;           // 4194304 = N
constexpr int kNCls = 11;
constexpr int kNQ = 2 * kNCls + 1;        // 0..10 S'_i (=768*S), 11..21 C_i, 22 ss' (=9*SS)
constexpr int kBlocks = 1024;             // 16 images x 64 slabs
constexpr int kThreads = 256;
constexpr int kIters = 4;                 // 4096 px per block

__global__ __launch_bounds__(kThreads) void seg_main_kernel(
    const float* __restrict__ x, const int* __restrict__ y,
    float* __restrict__ pd) {
  const int tid = threadIdx.x, bid = blockIdx.x;
  const int b = bid >> 6;                 // image index (64 slabs/image)
  const int basePix = (bid & 63) << 12;   // slab base within image (4096 px)
  const float* xb = x + (size_t)b * 3 * kHW + basePix;
  const int* yb = y + (size_t)b * kHW + basePix;

  unsigned acc[6] = {0u, 0u, 0u, 0u, 0u, 0u};  // classes (2r, 2r+1) in lo/hi 16
  unsigned long long pack = 0ull;         // 11 exact counts in 5-bit fields
  float ss = 0.f;

#pragma unroll
  for (int it = 0; it < kIters; ++it) {
    const int o = (it << 10) + (tid << 2);     // <= 4092 floats, imm-friendly
    const float4 x0 = *reinterpret_cast<const float4*>(xb + o);
    const float4 x1 = *reinterpret_cast<const float4*>(xb + kHW + o);
    const float4 x2 = *reinterpret_cast<const float4*>(xb + 2 * kHW + o);
    const int4 yv = *reinterpret_cast<const int4*>(yb + o);

    const float sv4[4] = {(x0.x + x1.x) + x2.x, (x0.y + x1.y) + x2.y,
                          (x0.z + x1.z) + x2.z, (x0.w + x1.w) + x2.w};
    const int yy[4] = {yv.x, yv.y, yv.z, yv.w};
#pragma unroll
    for (int j = 0; j < 4; ++j) {
      const float sv = sv4[j];            // = 3*m; sv==0 <=> m==0 exactly
      ss = fmaf(sv, sv, ss);              // 9*m^2; zero contributes zero
      const int cls = (sv != 0.f) ? yy[j] : 12;  // fold nz once; 12 = dead
      const unsigned q = (unsigned)fmaf(sv, 256.f, 0.5f);  // round(768*m)<=768
      const unsigned qsh = q << ((cls & 1) << 4);          // lo or hi half
      const int r = cls >> 1;             // target reg 0..5 (6 for dead)
#pragma unroll
      for (int rr = 0; rr < 6; ++rr)
        acc[rr] += (r == rr) ? qsh : 0u;  // cmp + cndmask + add
      pack += 1ull << (5 * cls);          // exact counts (field 12 dead)
    }
  }

  // ---- per-thread 23 quantities (all integer-exact in f32 except ss) ----
  float qv[kNQ];
#pragma unroll
  for (int r = 0; r < 6; ++r) {
    const unsigned lo = acc[r] & 0xFFFFu, hi = acc[r] >> 16;
    qv[2 * r] = (float)lo;                // classes 0,2,4,6,8,10
    if (2 * r + 1 < kNCls) qv[2 * r + 1] = (float)hi;  // 1,3,5,7,9
  }
#pragma unroll
  for (int i = 0; i < kNCls; ++i)
    qv[kNCls + i] = (float)((unsigned)(pack >> (5 * i)) & 31u);
  qv[2 * kNCls] = ss;

  // ---- block epilogue: LDS transpose, 8 lanes per quantity, f32-exact ----
  __shared__ float arr[kNQ][kThreads];
#pragma unroll
  for (int q = 0; q < kNQ; ++q) arr[q][tid] = qv[q];
  __syncthreads();

  if (tid < kNQ * 8) {
    const int q = tid >> 3, l = tid & 7;
    const float4* row = reinterpret_cast<const float4*>(arr[q]);
    float fv = 0.f;
#pragma unroll
    for (int jj = 0; jj < kThreads / 32; ++jj) {
      const float4 v = row[l + 8 * jj];
      fv += ((v.x + v.y) + (v.z + v.w)); // block class-sums <= 3.1M: f32-exact
    }
#pragma unroll
    for (int o = 4; o > 0; o >>= 1) fv += __shfl_down(fv, o, 8);
    if (l == 0) pd[(size_t)q * kBlocks + bid] = fv;  // quantity-major, f32
  }
}

__global__ __launch_bounds__(1024) void seg_final_kernel(
    const float* __restrict__ pd, float* __restrict__ out) {
  __shared__ double tot[kNQ];
  const int q = threadIdx.x >> 5;         // 32 lanes per quantity
  const int lane = threadIdx.x & 31;
  if (q < kNQ) {
    const float4* row = reinterpret_cast<const float4*>(pd + (size_t)q * kBlocks);
    double v = 0.0;
#pragma unroll
    for (int j = 0; j < kBlocks / 128; ++j) {   // 8 unrolled float4 loads
      const float4 f = row[lane + 32 * j];
      v += (double)((f.x + f.y) + (f.z + f.w));
    }
#pragma unroll
    for (int o = 16; o > 0; o >>= 1) v += __shfl_down(v, o, 32);
    if (lane == 0) tot[q] = v;
  }
  __syncthreads();
  if (threadIdx.x == 0) {
    const double N = (double)kNPix;
    double acc2 = tot[2 * kNCls] / 9.0;   // SS = ss'/9
    for (int i = 0; i < kNCls; ++i) {
      const double S = tot[i] / 768.0;    // S = (sum q)/768
      const double C = tot[kNCls + i];
      acc2 += S * S * (C / N - 2.0) / N;  // -2 S^2/N + C S^2/N^2
    }
    out[0] = (float)(acc2 / N);
  }
}

extern "C" void kernel_launch(void* const* d_in, const int* in_sizes, int n_in,
                              void* d_out, int out_size, void* d_ws, size_t ws_size,
                              hipStream_t stream) {
  const float* x = (const float*)d_in[0];
  const int* y = (const int*)d_in[1];
  float* out = (float*)d_out;
  float* pd = (float*)d_ws;               // 23 * 1024 * 4 = 94 KB

  seg_main_kernel<<<kBlocks, kThreads, 0, stream>>>(x, y, pd);
  seg_final_kernel<<<1, 1024, 0, stream>>>(pd, out);
}